// Round 5
// baseline (265.585 us; speedup 1.0000x reference)
//
#include <hip/hip_runtime.h>
#include <math.h>

// Problem constants (from reference)
#define BATCH 128
#define NI    1152
#define ND    8
#define NC    32
#define NE    16
#define NROUT 3

// Tiling: 128 threads = 32 c x 2 e-halves x 2 batch-groups; NB=4 batches each.
// One ds_read_b128 feeds 16 FMAs. ISPLIT=64 so plain-store partials fit in ws.
#define ISPLIT     64
#define ICHUNK     (NI / ISPLIT)    // 18
#define BT         8                // batches per block
#define NB         4                // batches per thread
#define RT_THREADS 128
#define WROW       132              // padded row stride: conflict-free (measured 0)
#define SQ_THREADS 256

template<int CTRL>
__device__ __forceinline__ float dpp_add(float v) {
    int t = __builtin_amdgcn_update_dpp(0, __float_as_int(v), CTRL, 0xF, 0xF, true);
    return v + __int_as_float(t);
}

// Sum over lane bits 0..4 (32 'c' lanes of each eh-half).
__device__ __forceinline__ float sum_over_c(float v) {
    v = dpp_add<0xB1>(v);    // lane ^ 1   quad_perm(1,0,3,2)
    v = dpp_add<0x4E>(v);    // lane ^ 2   quad_perm(2,3,0,1)
    v = dpp_add<0x141>(v);   // lane ^ 4   row_half_mirror
    v = dpp_add<0x140>(v);   // lane ^ 8   row_mirror
    int s = __builtin_amdgcn_ds_swizzle(__float_as_int(v), 0x401F); // lane ^ 16
    return v + __int_as_float(s);
}

// Sum over lane bits 0..3 (16 e-lanes) for squash.
__device__ __forceinline__ float sum_over_e16(float v) {
    v = dpp_add<0xB1>(v);
    v = dpp_add<0x4E>(v);
    v = dpp_add<0x141>(v);
    v = dpp_add<0x140>(v);
    return v;
}

// ---------------------------------------------------------------------------
// Fused routing iteration. W double-buffered in LDS (reg round-trip, padded,
// conflict-free). x via wave-uniform scalar loads. Softmax over c in-wave
// (DPP + 1 swizzle). Partial s written with plain float4 stores, one slice
// per ic block (atomic fallback only if ws too small).
// ---------------------------------------------------------------------------
__global__ __launch_bounds__(RT_THREADS, 2)
void route_iter_kernel(const float* __restrict__ x, const float* __restrict__ W,
                       const float* __restrict__ o_sum, float* __restrict__ s_part,
                       int iter, int nslice, int use_atomic)
{
    __shared__ float Ws[2][NC * WROW];   // 2 x 16.9 KB

    const int tid = threadIdx.x;
    const int c   = tid & 31;
    const int eh  = (tid >> 5) & 1;
    const int bp  = __builtin_amdgcn_readfirstlane(tid >> 6);  // wave-uniform
    const int ic  = blockIdx.x;
    const int bt  = blockIdx.y;
    const int i0  = ic * ICHUNK;
    const int b0  = bt * BT + bp * NB;   // 4 consecutive batches per wave
    const int e0  = eh * 8;

    // o_sum[b, c, e0..e0+7] in registers (iter > 0 only)
    float o_reg[NB][8];
    if (iter > 0) {
#pragma unroll
        for (int j = 0; j < NB; ++j) {
            const float4* op = (const float4*)(o_sum + ((size_t)(b0 + j) * NC + c) * NE + e0);
            float4 a = op[0], b = op[1];
            o_reg[j][0] = a.x; o_reg[j][1] = a.y; o_reg[j][2] = a.z; o_reg[j][3] = a.w;
            o_reg[j][4] = b.x; o_reg[j][5] = b.y; o_reg[j][6] = b.z; o_reg[j][7] = b.w;
        }
    }

    float s_acc[NB][8];
#pragma unroll
    for (int j = 0; j < NB; ++j)
#pragma unroll
        for (int e = 0; e < 8; ++e) s_acc[j][e] = 0.f;

    // ---- prologue: stage W[i0] into buffer 0 (8 float4 per thread) ----
    float4 pr[8];
    {
        const float4* src = (const float4*)(W + (size_t)i0 * (NC * ND * NE));
#pragma unroll
        for (int r = 0; r < 8; ++r) pr[r] = src[tid + r * RT_THREADS];
#pragma unroll
        for (int r = 0; r < 8; ++r) {
            int j = tid + r * RT_THREADS;            // float4 chunk 0..1023
            *(float4*)&Ws[0][(j >> 5) * WROW + (j & 31) * 4] = pr[r];
        }
    }

    for (int ii = 0; ii < ICHUNK; ++ii) {
        const int i = i0 + ii;

        // prefetch next W tile into registers (lands during compute)
        if (ii + 1 < ICHUNK) {
            const float4* src = (const float4*)(W + (size_t)(i + 1) * (NC * ND * NE));
#pragma unroll
            for (int r = 0; r < 8; ++r) pr[r] = src[tid + r * RT_THREADS];
        }

        // x rows: wave-uniform address -> scalar loads
        float xv[NB][ND];
#pragma unroll
        for (int j = 0; j < NB; ++j) {
            const float* xp = x + ((size_t)(b0 + j) * NI + i) * ND;
            float4 xa = *(const float4*)xp;
            float4 xb = *((const float4*)xp + 1);
            xv[j][0] = xa.x; xv[j][1] = xa.y; xv[j][2] = xa.z; xv[j][3] = xa.w;
            xv[j][4] = xb.x; xv[j][5] = xb.y; xv[j][6] = xb.z; xv[j][7] = xb.w;
        }

        __syncthreads();   // buf[ii&1] ready; previous readers done

        // ---- u_hat[b0..b0+3, c, e0..e0+7] ----
        const float* wr = &Ws[ii & 1][c * WROW + e0];
        float uh[NB][8];
#pragma unroll
        for (int j = 0; j < NB; ++j)
#pragma unroll
            for (int e = 0; e < 8; ++e) uh[j][e] = 0.f;

#pragma unroll
        for (int d = 0; d < ND; ++d) {
            float4 wa = *(const float4*)(wr + d * 16);
            float4 wb = *(const float4*)(wr + d * 16 + 4);
#pragma unroll
            for (int j = 0; j < NB; ++j) {
                const float xd = xv[j][d];
                uh[j][0] = fmaf(xd, wa.x, uh[j][0]);
                uh[j][1] = fmaf(xd, wa.y, uh[j][1]);
                uh[j][2] = fmaf(xd, wa.z, uh[j][2]);
                uh[j][3] = fmaf(xd, wa.w, uh[j][3]);
                uh[j][4] = fmaf(xd, wb.x, uh[j][4]);
                uh[j][5] = fmaf(xd, wb.y, uh[j][5]);
                uh[j][6] = fmaf(xd, wb.z, uh[j][6]);
                uh[j][7] = fmaf(xd, wb.w, uh[j][7]);
            }
        }

        // ---- routing weights + s accumulation ----
        if (iter > 0) {
#pragma unroll
            for (int j = 0; j < NB; ++j) {
                float lp = 0.f;
#pragma unroll
                for (int e = 0; e < 8; ++e) lp = fmaf(uh[j][e], o_reg[j][e], lp);
                lp += __shfl_xor(lp, 32);          // combine e-halves -> full logit
                float el = __expf(lp);             // |logit| small; no max-sub
                float den = sum_over_c(el);        // softmax denom over 32 c
                float wgt = el / den;
#pragma unroll
                for (int e = 0; e < 8; ++e) s_acc[j][e] = fmaf(wgt, uh[j][e], s_acc[j][e]);
            }
        } else {
            const float wgt = 1.f / 32.f;
#pragma unroll
            for (int j = 0; j < NB; ++j)
#pragma unroll
                for (int e = 0; e < 8; ++e) s_acc[j][e] = fmaf(wgt, uh[j][e], s_acc[j][e]);
        }

        // ---- write next W tile into the other buffer ----
        if (ii + 1 < ICHUNK) {
#pragma unroll
            for (int r = 0; r < 8; ++r) {
                int j = tid + r * RT_THREADS;
                *(float4*)&Ws[(ii + 1) & 1][(j >> 5) * WROW + (j & 31) * 4] = pr[r];
            }
        }
    }

    // ---- write partial s ----
    const int slice = use_atomic ? (ic & (nslice - 1)) : ic;
#pragma unroll
    for (int j = 0; j < NB; ++j) {
        float* base = s_part + (((size_t)slice * BATCH + (b0 + j)) * NC + c) * NE + e0;
        if (use_atomic) {
#pragma unroll
            for (int e = 0; e < 8; ++e) atomicAdd(base + e, s_acc[j][e]);
        } else {
            *(float4*)(base)     = make_float4(s_acc[j][0], s_acc[j][1], s_acc[j][2], s_acc[j][3]);
            *(float4*)(base + 4) = make_float4(s_acc[j][4], s_acc[j][5], s_acc[j][6], s_acc[j][7]);
        }
    }
}

// ---------------------------------------------------------------------------
// squash: reduce slices, squash, update o_sum / write output.
// One thread per output element; e-reduction via DPP (lane bits 0..3).
// ---------------------------------------------------------------------------
__global__ __launch_bounds__(SQ_THREADS)
void squash_kernel(float* __restrict__ s_part, float* __restrict__ o_sum,
                   float* __restrict__ out, int iter, int nslice, int zero_after)
{
    const int idx = blockIdx.x * SQ_THREADS + threadIdx.x;  // (b*32 + c)*16 + e

    float acc = 0.f;
#pragma unroll 4
    for (int k = 0; k < nslice; ++k) {
        float* p = s_part + (size_t)k * (BATCH * NC * NE) + idx;
        acc += *p;
        if (zero_after) *p = 0.f;
    }

    float q = sum_over_e16(acc * acc);
    // scale = s2/(1+s2)/sqrt(s2) == sqrt(s2)/(1+s2)
    float scale = sqrtf(q) / (1.f + q);
    float o = scale * acc;

    if (iter == NROUT - 1)      out[idx]   = o;
    else if (iter == 0)         o_sum[idx] = o;
    else                        o_sum[idx] += o;
}

extern "C" void kernel_launch(void* const* d_in, const int* in_sizes, int n_in,
                              void* d_out, int out_size, void* d_ws, size_t ws_size,
                              hipStream_t stream) {
    const float* x = (const float*)d_in[0];   // [128,1152,8]
    const float* W = (const float*)d_in[1];   // [1152,32,8,16]
    float* out = (float*)d_out;               // [128,32,16]

    const size_t slice_elems = (size_t)BATCH * NC * NE;   // 65536
    const size_t slice_bytes = slice_elems * sizeof(float);

    float* o_sum  = (float*)d_ws;
    float* s_part = o_sum + slice_elems;

    int nslice, use_atomic;
    if (ws_size >= slice_bytes * (ISPLIT + 1))  { nslice = ISPLIT; use_atomic = 0; }
    else if (ws_size >= slice_bytes * (32 + 1)) { nslice = 32; use_atomic = 1; }
    else if (ws_size >= slice_bytes * (8 + 1))  { nslice = 8;  use_atomic = 1; }
    else                                        { nslice = 1;  use_atomic = 1; }

    if (use_atomic)
        hipMemsetAsync(s_part, 0, slice_bytes * nslice, stream);

    for (int it = 0; it < NROUT; ++it) {
        route_iter_kernel<<<dim3(ISPLIT, BATCH / BT), RT_THREADS, 0, stream>>>(
            x, W, o_sum, s_part, it, nslice, use_atomic);
        squash_kernel<<<(BATCH * NC * NE) / SQ_THREADS, SQ_THREADS, 0, stream>>>(
            s_part, o_sum, out, it, nslice, use_atomic);
    }
}

// Round 6
// 168.230 us; speedup vs baseline: 1.5787x; 1.5787x over previous
//
#include <hip/hip_runtime.h>
#include <math.h>

// Problem constants (from reference)
#define BATCH 128
#define NI    1152
#define ND    8
#define NC    32
#define NE    16
#define NROUT 3

// Tiling: 256 threads = 32 c x 2 e-halves x 4 batch-groups; NB=4 batches each.
// One ds_read_b128 feeds 16 FMAs. ISPLIT=64 -> plain-store partials fit ws
// (65 x 256KB = 17.04 MB, verified fitting in round 3).
#define ISPLIT     64
#define ICHUNK     (NI / ISPLIT)    // 18
#define BT         16               // batches per block
#define NB         4                // batches per thread
#define RT_THREADS 256
#define WROW       132              // padded row stride: conflict-free (measured 0)
#define SQ_THREADS 256

template<int CTRL>
__device__ __forceinline__ float dpp_add(float v) {
    int t = __builtin_amdgcn_update_dpp(0, __float_as_int(v), CTRL, 0xF, 0xF, true);
    return v + __int_as_float(t);
}

// Sum over lane bits 0..4 (32 'c' lanes of each eh-half).
__device__ __forceinline__ float sum_over_c(float v) {
    v = dpp_add<0xB1>(v);    // lane ^ 1   quad_perm(1,0,3,2)
    v = dpp_add<0x4E>(v);    // lane ^ 2   quad_perm(2,3,0,1)
    v = dpp_add<0x141>(v);   // lane ^ 4   row_half_mirror
    v = dpp_add<0x140>(v);   // lane ^ 8   row_mirror
    int s = __builtin_amdgcn_ds_swizzle(__float_as_int(v), 0x401F); // lane ^ 16
    return v + __int_as_float(s);
}

// Sum over lane bits 0..3 (16 e-lanes) for squash.
__device__ __forceinline__ float sum_over_e16(float v) {
    v = dpp_add<0xB1>(v);
    v = dpp_add<0x4E>(v);
    v = dpp_add<0x141>(v);
    v = dpp_add<0x140>(v);
    return v;
}

// ---------------------------------------------------------------------------
// Fused routing iteration. W double-buffered in LDS (reg round-trip, padded,
// conflict-free). x via wave-uniform loads. Softmax over c in-wave (DPP + 1
// swizzle). Partial s written with plain float4 stores, one slice per ic.
// ---------------------------------------------------------------------------
__global__ __launch_bounds__(RT_THREADS, 2)
void route_iter_kernel(const float* __restrict__ x, const float* __restrict__ W,
                       const float* __restrict__ o_sum, float* __restrict__ s_part,
                       int iter, int nslice, int use_atomic)
{
    __shared__ float Ws[2][NC * WROW];   // 2 x 16.9 KB

    const int tid = threadIdx.x;
    const int c   = tid & 31;
    const int eh  = (tid >> 5) & 1;
    const int bp  = __builtin_amdgcn_readfirstlane(tid >> 6);  // wave-uniform
    const int ic  = blockIdx.x;
    const int bt  = blockIdx.y;
    const int i0  = ic * ICHUNK;
    const int b0  = bt * BT + bp * NB;   // 4 consecutive batches per wave
    const int e0  = eh * 8;

    // o_sum[b, c, e0..e0+7] in registers (iter > 0 only)
    float o_reg[NB][8];
    if (iter > 0) {
#pragma unroll
        for (int j = 0; j < NB; ++j) {
            const float4* op = (const float4*)(o_sum + ((size_t)(b0 + j) * NC + c) * NE + e0);
            float4 a = op[0], b = op[1];
            o_reg[j][0] = a.x; o_reg[j][1] = a.y; o_reg[j][2] = a.z; o_reg[j][3] = a.w;
            o_reg[j][4] = b.x; o_reg[j][5] = b.y; o_reg[j][6] = b.z; o_reg[j][7] = b.w;
        }
    }

    float s_acc[NB][8];
#pragma unroll
    for (int j = 0; j < NB; ++j)
#pragma unroll
        for (int e = 0; e < 8; ++e) s_acc[j][e] = 0.f;

    // ---- prologue: stage W[i0] into buffer 0 (4 float4 per thread) ----
    float4 pr[4];
    {
        const float4* src = (const float4*)(W + (size_t)i0 * (NC * ND * NE));
#pragma unroll
        for (int r = 0; r < 4; ++r) pr[r] = src[tid + r * RT_THREADS];
#pragma unroll
        for (int r = 0; r < 4; ++r) {
            int j = tid + r * RT_THREADS;            // float4 chunk 0..1023
            *(float4*)&Ws[0][(j >> 5) * WROW + (j & 31) * 4] = pr[r];
        }
    }

    for (int ii = 0; ii < ICHUNK; ++ii) {
        const int i = i0 + ii;

        // prefetch next W tile into registers (lands during compute)
        if (ii + 1 < ICHUNK) {
            const float4* src = (const float4*)(W + (size_t)(i + 1) * (NC * ND * NE));
#pragma unroll
            for (int r = 0; r < 4; ++r) pr[r] = src[tid + r * RT_THREADS];
        }

        // x rows: wave-uniform address -> broadcast loads
        float xv[NB][ND];
#pragma unroll
        for (int j = 0; j < NB; ++j) {
            const float* xp = x + ((size_t)(b0 + j) * NI + i) * ND;
            float4 xa = *(const float4*)xp;
            float4 xb = *((const float4*)xp + 1);
            xv[j][0] = xa.x; xv[j][1] = xa.y; xv[j][2] = xa.z; xv[j][3] = xa.w;
            xv[j][4] = xb.x; xv[j][5] = xb.y; xv[j][6] = xb.z; xv[j][7] = xb.w;
        }

        __syncthreads();   // buf[ii&1] ready; previous readers done

        // ---- u_hat[b0..b0+3, c, e0..e0+7] ----
        const float* wr = &Ws[ii & 1][c * WROW + e0];
        float uh[NB][8];
#pragma unroll
        for (int j = 0; j < NB; ++j)
#pragma unroll
            for (int e = 0; e < 8; ++e) uh[j][e] = 0.f;

#pragma unroll
        for (int d = 0; d < ND; ++d) {
            float4 wa = *(const float4*)(wr + d * 16);
            float4 wb = *(const float4*)(wr + d * 16 + 4);
#pragma unroll
            for (int j = 0; j < NB; ++j) {
                const float xd = xv[j][d];
                uh[j][0] = fmaf(xd, wa.x, uh[j][0]);
                uh[j][1] = fmaf(xd, wa.y, uh[j][1]);
                uh[j][2] = fmaf(xd, wa.z, uh[j][2]);
                uh[j][3] = fmaf(xd, wa.w, uh[j][3]);
                uh[j][4] = fmaf(xd, wb.x, uh[j][4]);
                uh[j][5] = fmaf(xd, wb.y, uh[j][5]);
                uh[j][6] = fmaf(xd, wb.z, uh[j][6]);
                uh[j][7] = fmaf(xd, wb.w, uh[j][7]);
            }
        }

        // ---- routing weights + s accumulation ----
        if (iter > 0) {
#pragma unroll
            for (int j = 0; j < NB; ++j) {
                float lp = 0.f;
#pragma unroll
                for (int e = 0; e < 8; ++e) lp = fmaf(uh[j][e], o_reg[j][e], lp);
                lp += __shfl_xor(lp, 32);          // combine e-halves -> full logit
                float el = __expf(lp);             // |logit| small; no max-sub
                float den = sum_over_c(el);        // softmax denom over 32 c
                float wgt = el / den;
#pragma unroll
                for (int e = 0; e < 8; ++e) s_acc[j][e] = fmaf(wgt, uh[j][e], s_acc[j][e]);
            }
        } else {
            const float wgt = 1.f / 32.f;
#pragma unroll
            for (int j = 0; j < NB; ++j)
#pragma unroll
                for (int e = 0; e < 8; ++e) s_acc[j][e] = fmaf(wgt, uh[j][e], s_acc[j][e]);
        }

        // ---- write next W tile into the other buffer ----
        if (ii + 1 < ICHUNK) {
#pragma unroll
            for (int r = 0; r < 4; ++r) {
                int j = tid + r * RT_THREADS;
                *(float4*)&Ws[(ii + 1) & 1][(j >> 5) * WROW + (j & 31) * 4] = pr[r];
            }
        }
    }

    // ---- write partial s ----
    const int slice = use_atomic ? (ic & (nslice - 1)) : ic;
#pragma unroll
    for (int j = 0; j < NB; ++j) {
        float* base = s_part + (((size_t)slice * BATCH + (b0 + j)) * NC + c) * NE + e0;
        if (use_atomic) {
#pragma unroll
            for (int e = 0; e < 8; ++e) atomicAdd(base + e, s_acc[j][e]);
        } else {
            *(float4*)(base)     = make_float4(s_acc[j][0], s_acc[j][1], s_acc[j][2], s_acc[j][3]);
            *(float4*)(base + 4) = make_float4(s_acc[j][4], s_acc[j][5], s_acc[j][6], s_acc[j][7]);
        }
    }
}

// ---------------------------------------------------------------------------
// squash: reduce slices, squash, update o_sum / write output.
// One thread per output element; e-reduction via DPP (lane bits 0..3).
// ---------------------------------------------------------------------------
__global__ __launch_bounds__(SQ_THREADS)
void squash_kernel(float* __restrict__ s_part, float* __restrict__ o_sum,
                   float* __restrict__ out, int iter, int nslice, int zero_after)
{
    const int idx = blockIdx.x * SQ_THREADS + threadIdx.x;  // (b*32 + c)*16 + e

    float acc = 0.f;
#pragma unroll 4
    for (int k = 0; k < nslice; ++k) {
        float* p = s_part + (size_t)k * (BATCH * NC * NE) + idx;
        acc += *p;
        if (zero_after) *p = 0.f;
    }

    float q = sum_over_e16(acc * acc);
    // scale = s2/(1+s2)/sqrt(s2) == sqrt(s2)/(1+s2)
    float scale = sqrtf(q) / (1.f + q);
    float o = scale * acc;

    if (iter == NROUT - 1)      out[idx]   = o;
    else if (iter == 0)         o_sum[idx] = o;
    else                        o_sum[idx] += o;
}

extern "C" void kernel_launch(void* const* d_in, const int* in_sizes, int n_in,
                              void* d_out, int out_size, void* d_ws, size_t ws_size,
                              hipStream_t stream) {
    const float* x = (const float*)d_in[0];   // [128,1152,8]
    const float* W = (const float*)d_in[1];   // [1152,32,8,16]
    float* out = (float*)d_out;               // [128,32,16]

    const size_t slice_elems = (size_t)BATCH * NC * NE;   // 65536
    const size_t slice_bytes = slice_elems * sizeof(float);

    float* o_sum  = (float*)d_ws;
    float* s_part = o_sum + slice_elems;

    int nslice, use_atomic;
    if (ws_size >= slice_bytes * (ISPLIT + 1))  { nslice = ISPLIT; use_atomic = 0; }
    else if (ws_size >= slice_bytes * (32 + 1)) { nslice = 32; use_atomic = 1; }
    else if (ws_size >= slice_bytes * (8 + 1))  { nslice = 8;  use_atomic = 1; }
    else                                        { nslice = 1;  use_atomic = 1; }

    if (use_atomic)
        hipMemsetAsync(s_part, 0, slice_bytes * nslice, stream);

    for (int it = 0; it < NROUT; ++it) {
        route_iter_kernel<<<dim3(ISPLIT, BATCH / BT), RT_THREADS, 0, stream>>>(
            x, W, o_sum, s_part, it, nslice, use_atomic);
        squash_kernel<<<(BATCH * NC * NE) / SQ_THREADS, SQ_THREADS, 0, stream>>>(
            s_part, o_sum, out, it, nslice, use_atomic);
    }
}